// Round 2
// baseline (2883.362 us; speedup 1.0000x reference)
//
#include <hip/hip_runtime.h>
#include <cstdint>
#include <cstddef>

typedef __bf16 bf16x8 __attribute__((ext_vector_type(8)));
typedef __bf16 bf16x4 __attribute__((ext_vector_type(4)));
typedef float  f32x4  __attribute__((ext_vector_type(4)));

// ---------------- ws layout (bytes) ----------------
#define WS_WFRAG   0            // 12,582,912 : fused W bf16 fragments
#define WS_XB      12582912     // 16,777,216 : x in bf16
#define WS_XCHG    29360128     // 33,554,432 : 512 slots * 64 KiB (fresh h exchange)
#define WS_NEEDED  62914560

// LDS layout (bytes): H @0 (32768) | W @32768 (98304) | scr @131072 (2176)
#define LDS_BYTES  133248

#define SENT 0xFFFFFFFFFFFFFFFFULL

__device__ __forceinline__ void gload16(const void* g, void* l) {
    __builtin_amdgcn_global_load_lds(
        (const __attribute__((address_space(1))) void*)(g),
        (__attribute__((address_space(3))) void*)(l),
        16, 0, 0);
}

__device__ __forceinline__ float sigmoidf_(float x) {
    return 1.f / (1.f + __expf(-x));
}
__device__ __forceinline__ float tanhf_(float x) {
    x = fminf(fmaxf(x, -15.f), 15.f);
    float e2 = __expf(2.f * x);
    return (e2 - 1.f) / (e2 + 1.f);
}

__device__ __forceinline__ bf16x8 mkfrag(unsigned long long lo, unsigned long long hi) {
    union { unsigned long long u[2]; bf16x8 v; } x;
    x.u[0] = lo; x.u[1] = hi;
    return x.v;
}

// ---- prep: shuffle fused W = [Wx ; Wh] into bf16 B-fragment order ----
__global__ void __launch_bounds__(256) prep_w_kernel(const float* __restrict__ Wx,
                                                     const float* __restrict__ Wh,
                                                     __bf16* __restrict__ wfrag) {
    int tid = blockIdx.x * 256 + threadIdx.x;   // 0 .. 786431
    int l   = tid & 63;
    int m   = tid >> 6;
    int nt  = m & 1;
    int sk  = m >> 1;
    int kk  = sk % 48;
    int s   = sk / 48;
    int lc  = l & 15;
    int c   = nt * 16 + lc;
    int uu  = c >> 2;
    int gi  = c & 3;
    int n   = gi * 1024 + s * 8 + uu;
    int k0  = kk * 32 + (l >> 4) * 8;
    bf16x8 v;
#pragma unroll
    for (int j = 0; j < 8; ++j) {
        int k  = k0 + j;
        float f = (k < 512) ? Wx[k * 4096 + n] : Wh[(k - 512) * 4096 + n];
        v[j] = (__bf16)f;
    }
    ((bf16x8*)wfrag)[tid] = v;
}

// ---- prep: cast data fp32 -> bf16 ----
__global__ void __launch_bounds__(256) prep_x_kernel(const float* __restrict__ data,
                                                     __bf16* __restrict__ xb) {
    int tid = blockIdx.x * 256 + threadIdx.x;
    float4 v = ((const float4*)data)[tid];
    bf16x4 o;
    o[0] = (__bf16)v.x; o[1] = (__bf16)v.y; o[2] = (__bf16)v.z; o[3] = (__bf16)v.w;
    ((bf16x4*)xb)[tid] = o;
}

// ---- persistent LSTM kernel ----
// grid = 256 blocks x 128 threads. block -> (g = bid>>7, s = bid&127).
// Pure dataflow sync: no counters, no polls, no producer waitcnt.
//  * xchg slot t is sentinel-prefilled (0xFF). Producers fire-and-forget
//    agent-scope 8B stores; consumers retry agent-scope loads until the word
//    != sentinel. Real h is bounded in (-1,1) -> bf16 0xFFFF impossible.
//  * Each thread's bypass-loaded 16B h word IS its MFMA A-fragment (index
//    identity), so h stays in registers; LDS staging only for the partner
//    wave's 16 chunks. x A-fragments load global->reg one step ahead.
//  * ONE __syncthreads per step (H_lds write -> partner read). The next
//    step's H_lds overwrite is ordered by dataflow: a wave passes retry(t+1)
//    only after BOTH waves of every block stored h_{t+1}, which is after the
//    partner finished reading H_lds for step t.
__global__ void __launch_bounds__(128)
lstm_main(const __bf16* __restrict__ xb, const __bf16* __restrict__ wfrag,
          const float* __restrict__ bias, float* __restrict__ out,
          __bf16* __restrict__ hbuf) {
    extern __shared__ char smem[];
    __bf16* H_lds = (__bf16*)smem;                 // 32 chunks * 512 bf16
    __bf16* W_lds = (__bf16*)(smem + 32768);       // 96 chunks * 512 bf16
    float*  scr   = (float*)(smem + 131072);       // 2 * 272 floats (wave-local)

    const int tid = threadIdx.x;
    const int l   = tid & 63;
    const int w   = tid >> 6;        // wave id == N-tile id (0,1)
    const int q   = l >> 4;
    const int r   = l & 15;
    const int bid = blockIdx.x;
    const int s   = bid & 127;
    const int g   = bid >> 7;
    const int gb0 = g * 16;

    // ---- stage W slice into LDS (once) ----
    const __bf16* wsrc = wfrag + (size_t)s * 49152;
    for (int m = w * 48; m < w * 48 + 48; ++m) {
        gload16(wsrc + m * 512 + l * 8, W_lds + m * 512);
    }

    const int uu = w * 4 + q;
    const int u  = s * 8 + uu;
    const float b_i = bias[u];
    const float b_f = bias[1024 + u];
    const float b_g = bias[2048 + u];
    const float b_o = bias[3072 + u];
    float cst = 0.f;

    // ---- x fragments for t=0: direct global->reg (A-frag identity) ----
    const __bf16* xrow = xb + (size_t)(gb0 + r) * 512 * 512;   // + t*512 + m*32 + q*8
    bf16x8 xfrag[16];
#pragma unroll
    for (int m = 0; m < 16; ++m)
        xfrag[m] = *(const bf16x8*)(xrow + m * 32 + q * 8);

    // ---- issue h_0 loads (slot 0 is zero-filled: no sentinel, passes at once) ----
    const char* xch = (const char*)hbuf;
    unsigned long long va[16], vb[16];
    {
        const char* hsrc = xch + (size_t)g * 32768;
#pragma unroll
        for (int j = 0; j < 16; ++j) {
            int m = w * 16 + j;
            const unsigned long long* p =
                (const unsigned long long*)(hsrc + (m * 4 + q) * 256 + r * 16);
            va[j] = __hip_atomic_load(p,     __ATOMIC_RELAXED, __HIP_MEMORY_SCOPE_AGENT);
            vb[j] = __hip_atomic_load(p + 1, __ATOMIC_RELAXED, __HIP_MEMORY_SCOPE_AGENT);
        }
    }

    __syncthreads();   // W staged (drains gload16 vmcnt)

    for (int t = 0; t < 512; ++t) {
        // ---- x-part MFMAs (registers; overlaps in-flight h loads) ----
        f32x4 acc0 = {0.f, 0.f, 0.f, 0.f};
        f32x4 acc1 = {0.f, 0.f, 0.f, 0.f};
#pragma unroll
        for (int kk = 0; kk < 16; kk += 2) {
            acc0 = __builtin_amdgcn_mfma_f32_16x16x32_bf16(
                xfrag[kk],     *(const bf16x8*)(W_lds + (kk * 2 + w) * 512 + l * 8), acc0, 0, 0, 0);
            acc1 = __builtin_amdgcn_mfma_f32_16x16x32_bf16(
                xfrag[kk + 1], *(const bf16x8*)(W_lds + ((kk + 1) * 2 + w) * 512 + l * 8), acc1, 0, 0, 0);
        }

        // ---- retry h_t until all 32 words are non-sentinel ----
        {
            const char* hsrc = xch + (size_t)t * 65536 + (size_t)g * 32768;
            for (;;) {
                int miss = 0;
#pragma unroll
                for (int j = 0; j < 16; ++j)
                    miss += (va[j] == SENT) + (vb[j] == SENT);
                if (miss == 0) break;
#pragma unroll
                for (int j = 0; j < 16; ++j) {
                    int m = w * 16 + j;
                    const unsigned long long* p =
                        (const unsigned long long*)(hsrc + (m * 4 + q) * 256 + r * 16);
                    if (va[j] == SENT)
                        va[j] = __hip_atomic_load(p,     __ATOMIC_RELAXED, __HIP_MEMORY_SCOPE_AGENT);
                    if (vb[j] == SENT)
                        vb[j] = __hip_atomic_load(p + 1, __ATOMIC_RELAXED, __HIP_MEMORY_SCOPE_AGENT);
                }
            }
        }

        // ---- stage own 16 chunks into LDS for the partner wave ----
#pragma unroll
        for (int j = 0; j < 16; ++j) {
            int m = w * 16 + j;
            unsigned long long tmp[2] = {va[j], vb[j]};
            *((ulonglong2*)(H_lds + m * 512 + l * 8)) = *(const ulonglong2*)tmp;
        }
        __syncthreads();   // the ONLY per-step barrier

        // ---- reload x fragments for t+1 (consumed next iteration) ----
        if (t < 511) {
#pragma unroll
            for (int m = 0; m < 16; ++m)
                xfrag[m] = *(const bf16x8*)(xrow + (size_t)(t + 1) * 512 + m * 32 + q * 8);
        }

        // ---- h-part MFMAs, kk-ascending (bit-identical accumulation order) ----
        if (w == 0) {
            // kk 16..31 = own chunks (regs), kk 32..47 = partner (LDS)
#pragma unroll
            for (int j = 0; j < 16; j += 2) {
                int kk = 16 + j;
                acc0 = __builtin_amdgcn_mfma_f32_16x16x32_bf16(
                    mkfrag(va[j], vb[j]),         *(const bf16x8*)(W_lds + (kk * 2 + 0) * 512 + l * 8), acc0, 0, 0, 0);
                acc1 = __builtin_amdgcn_mfma_f32_16x16x32_bf16(
                    mkfrag(va[j + 1], vb[j + 1]), *(const bf16x8*)(W_lds + ((kk + 1) * 2 + 0) * 512 + l * 8), acc1, 0, 0, 0);
            }
#pragma unroll
            for (int j = 0; j < 16; j += 2) {
                int mP = 16 + j, kk = 32 + j;
                acc0 = __builtin_amdgcn_mfma_f32_16x16x32_bf16(
                    *(const bf16x8*)(H_lds + mP * 512 + l * 8),       *(const bf16x8*)(W_lds + (kk * 2 + 0) * 512 + l * 8), acc0, 0, 0, 0);
                acc1 = __builtin_amdgcn_mfma_f32_16x16x32_bf16(
                    *(const bf16x8*)(H_lds + (mP + 1) * 512 + l * 8), *(const bf16x8*)(W_lds + ((kk + 1) * 2 + 0) * 512 + l * 8), acc1, 0, 0, 0);
            }
        } else {
            // kk 16..31 = partner (LDS), kk 32..47 = own chunks (regs)
#pragma unroll
            for (int j = 0; j < 16; j += 2) {
                int mP = j, kk = 16 + j;
                acc0 = __builtin_amdgcn_mfma_f32_16x16x32_bf16(
                    *(const bf16x8*)(H_lds + mP * 512 + l * 8),       *(const bf16x8*)(W_lds + (kk * 2 + 1) * 512 + l * 8), acc0, 0, 0, 0);
                acc1 = __builtin_amdgcn_mfma_f32_16x16x32_bf16(
                    *(const bf16x8*)(H_lds + (mP + 1) * 512 + l * 8), *(const bf16x8*)(W_lds + ((kk + 1) * 2 + 1) * 512 + l * 8), acc1, 0, 0, 0);
            }
#pragma unroll
            for (int j = 0; j < 16; j += 2) {
                int kk = 32 + j;
                acc0 = __builtin_amdgcn_mfma_f32_16x16x32_bf16(
                    mkfrag(va[j], vb[j]),         *(const bf16x8*)(W_lds + (kk * 2 + 1) * 512 + l * 8), acc0, 0, 0, 0);
                acc1 = __builtin_amdgcn_mfma_f32_16x16x32_bf16(
                    mkfrag(va[j + 1], vb[j + 1]), *(const bf16x8*)(W_lds + ((kk + 1) * 2 + 1) * 512 + l * 8), acc1, 0, 0, 0);
            }
        }

        // ---- regroup gates via wave-local scratch (no cross-wave access) ----
        float* sw = scr + w * 272;
#pragma unroll
        for (int rg = 0; rg < 4; ++rg) {
            sw[(l & 15) * 17 + q * 4 + rg] = acc0[rg] + acc1[rg];
        }
        float xi = sw[(q * 4 + 0) * 17 + r];
        float xf = sw[(q * 4 + 1) * 17 + r];
        float xg = sw[(q * 4 + 2) * 17 + r];
        float xo = sw[(q * 4 + 3) * 17 + r];

        float ii = sigmoidf_(xi + b_i);
        float ff = sigmoidf_(xf + b_f);
        float gg = tanhf_(xg + b_g);
        float oo = sigmoidf_(xo + b_o);
        cst = ff * cst + ii * gg;
        float h = oo * tanhf_(cst);

        // ---- pack h via shuffles; q==0 lanes fire-and-forget 8B store ----
        if (t < 511) {
            float h1 = __shfl_xor(h, 16);
            float h2 = __shfl_xor(h, 32);
            float h3 = __shfl_xor(h, 48);
            if ((l & 48) == 0) {
                union { bf16x4 v; unsigned long long u; } pk;
                pk.v[0] = (__bf16)h;  pk.v[1] = (__bf16)h1;
                pk.v[2] = (__bf16)h2; pk.v[3] = (__bf16)h3;
                unsigned long long* dst = (unsigned long long*)
                    ((char*)hbuf + (size_t)(t + 1) * 65536 + (size_t)g * 32768 + s * 256 + r * 16 + w * 8);
                __hip_atomic_store(dst, pk.u, __ATOMIC_RELAXED, __HIP_MEMORY_SCOPE_AGENT);
            }

            // ---- issue h_{t+1} loads now; retry next iteration absorbs latency ----
            const char* hn = xch + (size_t)(t + 1) * 65536 + (size_t)g * 32768;
#pragma unroll
            for (int j = 0; j < 16; ++j) {
                int m = w * 16 + j;
                const unsigned long long* p =
                    (const unsigned long long*)(hn + (m * 4 + q) * 256 + r * 16);
                va[j] = __hip_atomic_load(p,     __ATOMIC_RELAXED, __HIP_MEMORY_SCOPE_AGENT);
                vb[j] = __hip_atomic_load(p + 1, __ATOMIC_RELAXED, __HIP_MEMORY_SCOPE_AGENT);
            }
        }

        out[((size_t)(gb0 + r) * 512 + t) * 1024 + u] = h;
    }
}

extern "C" void kernel_launch(void* const* d_in, const int* in_sizes, int n_in,
                              void* d_out, int out_size, void* d_ws, size_t ws_size,
                              hipStream_t stream) {
    const float* data = (const float*)d_in[0];
    const float* Wx   = (const float*)d_in[1];
    const float* Wh   = (const float*)d_in[2];
    const float* b    = (const float*)d_in[3];
    float* out = (float*)d_out;

    if (ws_size < (size_t)WS_NEEDED) return;

    char* ws = (char*)d_ws;
    __bf16* wfrag = (__bf16*)(ws + WS_WFRAG);
    __bf16* xbuf  = (__bf16*)(ws + WS_XB);
    __bf16* xchg  = (__bf16*)(ws + WS_XCHG);

    hipFuncSetAttribute((const void*)lstm_main,
                        hipFuncAttributeMaxDynamicSharedMemorySize, LDS_BYTES);

    prep_w_kernel<<<3072, 256, 0, stream>>>(Wx, Wh, wfrag);
    prep_x_kernel<<<8192, 256, 0, stream>>>(data, xbuf);
    hipMemsetAsync(ws + WS_XCHG, 0x00, 65536, stream);                    // slot 0: h_0 = 0
    hipMemsetAsync(ws + WS_XCHG + 65536, 0xFF, 33554432 - 65536, stream); // slots 1..511: sentinel

    lstm_main<<<256, 128, LDS_BYTES, stream>>>(xbuf, wfrag, b, out, xchg);
}

// Round 3
// 2171.227 us; speedup vs baseline: 1.3280x; 1.3280x over previous
//
#include <hip/hip_runtime.h>
#include <cstdint>
#include <cstddef>

typedef __bf16 bf16x8 __attribute__((ext_vector_type(8)));
typedef __bf16 bf16x4 __attribute__((ext_vector_type(4)));
typedef float  f32x4  __attribute__((ext_vector_type(4)));

// ---------------- ws layout (bytes) ----------------
#define WS_WFRAG   0            // 12,582,912 : fused W bf16 fragments
#define WS_XB      12582912     // 16,777,216 : x in bf16
#define WS_XCHG    29360128     // 33,554,432 : 512 slots * 64 KiB (fresh h exchange)
#define WS_CNT     62914560     // 4,096      : counters
#define WS_NEEDED  62918656

// LDS layout (bytes): X dbuf @0 (32768) | Wx @32768 (32768) | scr @65536 (2176)
#define LDS_BYTES  67712

__device__ __forceinline__ void gload16(const void* g, void* l) {
    __builtin_amdgcn_global_load_lds(
        (const __attribute__((address_space(1))) void*)(g),
        (__attribute__((address_space(3))) void*)(l),
        16, 0, 0);
}

__device__ __forceinline__ float sigmoidf_(float x) {
    return 1.f / (1.f + __expf(-x));
}
__device__ __forceinline__ float tanhf_(float x) {
    x = fminf(fmaxf(x, -15.f), 15.f);
    float e2 = __expf(2.f * x);
    return (e2 - 1.f) / (e2 + 1.f);
}

// ---- prep: shuffle fused W = [Wx ; Wh] into bf16 B-fragment order ----
__global__ void __launch_bounds__(256) prep_w_kernel(const float* __restrict__ Wx,
                                                     const float* __restrict__ Wh,
                                                     __bf16* __restrict__ wfrag) {
    int tid = blockIdx.x * 256 + threadIdx.x;   // 0 .. 786431
    int l   = tid & 63;
    int m   = tid >> 6;
    int nt  = m & 1;
    int sk  = m >> 1;
    int kk  = sk % 48;
    int s   = sk / 48;
    int lc  = l & 15;
    int c   = nt * 16 + lc;
    int uu  = c >> 2;
    int gi  = c & 3;
    int n   = gi * 1024 + s * 8 + uu;
    int k0  = kk * 32 + (l >> 4) * 8;
    bf16x8 v;
#pragma unroll
    for (int j = 0; j < 8; ++j) {
        int k  = k0 + j;
        float f = (k < 512) ? Wx[k * 4096 + n] : Wh[(k - 512) * 4096 + n];
        v[j] = (__bf16)f;
    }
    ((bf16x8*)wfrag)[tid] = v;
}

// ---- prep: cast data fp32 -> bf16 ----
__global__ void __launch_bounds__(256) prep_x_kernel(const float* __restrict__ data,
                                                     __bf16* __restrict__ xb) {
    int tid = blockIdx.x * 256 + threadIdx.x;
    float4 v = ((const float4*)data)[tid];
    bf16x4 o;
    o[0] = (__bf16)v.x; o[1] = (__bf16)v.y; o[2] = (__bf16)v.z; o[3] = (__bf16)v.w;
    ((bf16x4*)xb)[tid] = o;
}

// ---- persistent LSTM kernel ----
// grid = 256 blocks x 128 threads. block -> (g = bid>>7, s = bid&127).
// R1's proven counter barrier + R2's proven register dataflow:
//  * Wh B-fragments (32 chunks) in registers -> no per-step W LDS reads.
//  * h_t loaded with plain cached loads straight into A-fragment registers
//    (fresh address per step -> never stale; both waves load the same chunks,
//    merged by L1/L2/MSHR). No H_lds staging, no staging barrier.
//  * Producer: shuffle-pack -> 8B agent store -> wave-level vmcnt(0) ->
//    per-wave counter add (target 256*t). ONE __syncthreads per step (release;
//    also drains the x-prefetch DMA into the other X buffer).
__global__ void __launch_bounds__(128, 1)
lstm_main(const __bf16* __restrict__ xb, const __bf16* __restrict__ wfrag,
          const float* __restrict__ bias, float* __restrict__ out,
          __bf16* __restrict__ hbuf, unsigned* __restrict__ cnt) {
    extern __shared__ char smem[];
    __bf16* X_lds = (__bf16*)smem;                 // 2 buffers * 16 chunks * 512 bf16
    __bf16* W_lds = (__bf16*)(smem + 32768);       // 32 chunks (kk 0..15, both nt)
    float*  scr   = (float*)(smem + 65536);        // 2 * 272 floats (wave-local)

    const int tid = threadIdx.x;
    const int l   = tid & 63;
    const int w   = tid >> 6;        // wave id == N-tile id (0,1)
    const int q   = l >> 4;
    const int r   = l & 15;
    const int bid = blockIdx.x;
    const int s   = bid & 127;
    const int g   = bid >> 7;
    const int gb0 = g * 16;

    const __bf16* wsrc = wfrag + (size_t)s * 49152;
    // ---- stage Wx part (chunks 0..31 = kk 0..15 x {nt0,nt1}) into LDS ----
    for (int m = w * 16; m < w * 16 + 16; ++m) {
        gload16(wsrc + m * 512 + l * 8, W_lds + m * 512);
    }
    // ---- Wh part in registers: chunk ((16+j)*2 + w), j = kk-16 ----
    bf16x8 wreg[32];
#pragma unroll
    for (int j = 0; j < 32; ++j)
        wreg[j] = *(const bf16x8*)(wsrc + (size_t)((16 + j) * 2 + w) * 512 + l * 8);

    const int uu = w * 4 + q;
    const int u  = s * 8 + uu;
    const float b_i = bias[u];
    const float b_f = bias[1024 + u];
    const float b_g = bias[2048 + u];
    const float b_o = bias[3072 + u];
    float cst = 0.f;

    unsigned* cbase = cnt + g * 512;             // 8 lines * 64 uints
    unsigned* mycnt = cbase + (s & 7) * 64;

    // ---- prefetch x_0 into X buffer 0 ----
    const __bf16* xrow = xb + (size_t)(gb0 + r) * 512 * 512;
#pragma unroll
    for (int j = 0; j < 8; ++j) {
        int m = w * 8 + j;
        gload16(xrow + m * 32 + q * 8, X_lds + m * 512);
    }

    const char* xch = (const char*)hbuf;
    __syncthreads();   // W + x_0 staged (drains vmcnt)

    for (int t = 0; t < 512; ++t) {
        const char* hsrc = xch + (size_t)t * 65536 + (size_t)g * 32768;

        // ---- issue first-half h_t loads (plain cached; addr fresh per step) ----
        bf16x8 hfA[16], hfB[16];
#pragma unroll
        for (int j = 0; j < 16; ++j)
            hfA[j] = *(const bf16x8*)(hsrc + (j * 4 + q) * 256 + r * 16);

        // ---- x-part MFMAs (A from X_lds, B from W_lds) overlap h-load flight ----
        const __bf16* Xc = X_lds + (t & 1) * 8192;
        f32x4 acc0 = {0.f, 0.f, 0.f, 0.f};
        f32x4 acc1 = {0.f, 0.f, 0.f, 0.f};
#pragma unroll
        for (int kk = 0; kk < 16; kk += 2) {
            acc0 = __builtin_amdgcn_mfma_f32_16x16x32_bf16(
                *(const bf16x8*)(Xc + kk * 512 + l * 8),
                *(const bf16x8*)(W_lds + (kk * 2 + w) * 512 + l * 8), acc0, 0, 0, 0);
            acc1 = __builtin_amdgcn_mfma_f32_16x16x32_bf16(
                *(const bf16x8*)(Xc + (kk + 1) * 512 + l * 8),
                *(const bf16x8*)(W_lds + ((kk + 1) * 2 + w) * 512 + l * 8), acc1, 0, 0, 0);
        }

        // ---- issue second-half h_t loads ----
#pragma unroll
        for (int j = 0; j < 16; ++j)
            hfB[j] = *(const bf16x8*)(hsrc + ((16 + j) * 4 + q) * 256 + r * 16);

        // ---- h-part MFMAs, kk ascending, acc0=even / acc1=odd (order preserved) ----
#pragma unroll
        for (int j = 0; j < 16; j += 2) {
            acc0 = __builtin_amdgcn_mfma_f32_16x16x32_bf16(hfA[j],     wreg[j],     acc0, 0, 0, 0);
            acc1 = __builtin_amdgcn_mfma_f32_16x16x32_bf16(hfA[j + 1], wreg[j + 1], acc1, 0, 0, 0);
        }
#pragma unroll
        for (int j = 0; j < 16; j += 2) {
            acc0 = __builtin_amdgcn_mfma_f32_16x16x32_bf16(hfB[j],     wreg[16 + j],     acc0, 0, 0, 0);
            acc1 = __builtin_amdgcn_mfma_f32_16x16x32_bf16(hfB[j + 1], wreg[16 + j + 1], acc1, 0, 0, 0);
        }

        // ---- regroup gates via wave-local scratch ----
        float* sw = scr + w * 272;
#pragma unroll
        for (int rg = 0; rg < 4; ++rg) {
            sw[(l & 15) * 17 + q * 4 + rg] = acc0[rg] + acc1[rg];
        }
        float xi = sw[(q * 4 + 0) * 17 + r];
        float xf = sw[(q * 4 + 1) * 17 + r];
        float xg = sw[(q * 4 + 2) * 17 + r];
        float xo = sw[(q * 4 + 3) * 17 + r];

        float ii = sigmoidf_(xi + b_i);
        float ff = sigmoidf_(xf + b_f);
        float gg = tanhf_(xg + b_g);
        float oo = sigmoidf_(xo + b_o);
        cst = ff * cst + ii * gg;
        float h = oo * tanhf_(cst);

        if (t < 511) {
            // ---- pack h via shuffles; q-lanes 0..15 of EACH wave store 8B ----
            float h1 = __shfl_xor(h, 16);
            float h2 = __shfl_xor(h, 32);
            float h3 = __shfl_xor(h, 48);
            if ((l & 48) == 0) {
                union { bf16x4 v; unsigned long long u; } pk;
                pk.v[0] = (__bf16)h;  pk.v[1] = (__bf16)h1;
                pk.v[2] = (__bf16)h2; pk.v[3] = (__bf16)h3;
                unsigned long long* dst = (unsigned long long*)
                    ((char*)hbuf + (size_t)(t + 1) * 65536 + (size_t)g * 32768 + s * 256 + r * 16 + w * 8);
                __hip_atomic_store(dst, pk.u, __ATOMIC_RELAXED, __HIP_MEMORY_SCOPE_AGENT);
            }
            // wave-level drain: own h stores acked at coherent point
            __asm__ __volatile__("s_waitcnt vmcnt(0)" ::: "memory");
            if (l == 0) {   // each wave signals independently (target 256/step)
                __hip_atomic_fetch_add(mycnt, 1u, __ATOMIC_RELAXED, __HIP_MEMORY_SCOPE_AGENT);
            }
            // ---- off-critical-path work overlapping the poll ----
            out[((size_t)(gb0 + r) * 512 + t) * 1024 + u] = h;
            {   // prefetch x_{t+1} into X[(t+1)&1]
                __bf16* Xn = X_lds + ((t + 1) & 1) * 8192;
#pragma unroll
                for (int j = 0; j < 8; ++j) {
                    int m = w * 8 + j;
                    gload16(xrow + (size_t)(t + 1) * 512 + m * 32 + q * 8, Xn + m * 512);
                }
            }
            if (tid == 0) {
                const unsigned target = 256u * (unsigned)(t + 1);
                for (;;) {
                    unsigned sum = 0;
#pragma unroll
                    for (int i = 0; i < 8; ++i)
                        sum += __hip_atomic_load(cbase + i * 64, __ATOMIC_RELAXED,
                                                 __HIP_MEMORY_SCOPE_AGENT);
                    if (sum >= target) break;
                }
            }
            __syncthreads();   // release: h_{t+1} visible; x prefetch drained
        } else {
            out[((size_t)(gb0 + r) * 512 + t) * 1024 + u] = h;
        }
    }
}

extern "C" void kernel_launch(void* const* d_in, const int* in_sizes, int n_in,
                              void* d_out, int out_size, void* d_ws, size_t ws_size,
                              hipStream_t stream) {
    const float* data = (const float*)d_in[0];
    const float* Wx   = (const float*)d_in[1];
    const float* Wh   = (const float*)d_in[2];
    const float* b    = (const float*)d_in[3];
    float* out = (float*)d_out;

    if (ws_size < (size_t)WS_NEEDED) return;

    char* ws = (char*)d_ws;
    __bf16*   wfrag = (__bf16*)(ws + WS_WFRAG);
    __bf16*   xbuf  = (__bf16*)(ws + WS_XB);
    __bf16*   xchg  = (__bf16*)(ws + WS_XCHG);
    unsigned* cnt   = (unsigned*)(ws + WS_CNT);

    hipFuncSetAttribute((const void*)lstm_main,
                        hipFuncAttributeMaxDynamicSharedMemorySize, LDS_BYTES);

    prep_w_kernel<<<3072, 256, 0, stream>>>(Wx, Wh, wfrag);
    prep_x_kernel<<<8192, 256, 0, stream>>>(data, xbuf);
    hipMemsetAsync(ws + WS_XCHG, 0x00, 65536, stream);   // slot 0: h_0 = 0
    hipMemsetAsync(ws + WS_CNT,  0x00, 4096,  stream);   // counters = 0

    lstm_main<<<256, 128, LDS_BYTES, stream>>>(xbuf, wfrag, b, out, xchg, cnt);
}